// Round 5
// baseline (42.287 us; speedup 1.0000x reference)
//
#include <hip/hip_runtime.h>
#include <math.h>

#define HWSZ 262144          // 512*512
#define NCOPY 16             // partial accumulator copies to spread atomics
#define LAMBD 0.005f
#define SMOOTH 1e-6f
#define ITERS 4              // 16 pixels per wave-iter -> 64 pixels per wave

typedef __attribute__((ext_vector_type(8))) short bf16x8;
typedef __attribute__((ext_vector_type(4))) float f32x4;

// v_rcp_f32: <=1 ulp approx reciprocal, 1 instr vs ~9-instr IEEE div
static __device__ __forceinline__ float rcp_hw(float x) {
    float r; asm("v_rcp_f32 %0, %1" : "=v"(r) : "v"(x)); return r;
}
// v_cvt_pk_bf16_f32: 2 f32 -> packed 2x bf16 (RTE), 1 instr
static __device__ __forceinline__ unsigned int pk_bf16(float lo, float hi) {
    unsigned int r;
    asm("v_cvt_pk_bf16_f32 %0, %1, %2" : "=v"(r) : "v"(lo), "v"(hi));
    return r;
}

// Barrier-free, LDS-free main loop. Lane (r = l&15, g = l>>4) owns batch r,
// pixels 4g..4g+3 of the wave's window: its pk-packed p/q values ARE the
// 16x16x32 MFMA A/B fragments (k-bijection chosen to match the float4 load;
// Gram is invariant since A and B use the same registers). G symmetric ->
// 3 MFMAs (PP, PQ, QQ) per K-block; QP handled analytically in the epilogue.
__global__ __launch_bounds__(256) void gram_kernel(
    const float* __restrict__ X,   // input  [16][4][512][512]
    const float* __restrict__ T,   // target [16][4][512][512]
    float* __restrict__ Gpart)     // [NCOPY][3][16][16]
{
    const int tid  = threadIdx.x;
    const int lane = tid & 63;
    const int wv   = tid >> 6;
    const int r    = lane & 15;    // batch = MFMA row/col index
    const int g    = lane >> 4;    // k-group: lane supplies pixels 4g..4g+3

    const int waveId = blockIdx.x * 4 + wv;
    const size_t base = (size_t)waveId * 64 + g * 4;

    const float* Xb = X + (size_t)r * 4 * HWSZ + base;
    const float* Tb = T + (size_t)r * 4 * HWSZ + base;

    f32x4 accPP = {0,0,0,0}, accPQ = {0,0,0,0}, accQQ = {0,0,0,0};

    f32x4 fin[2][4], ttn[2][4];    // ping-pong staging (static idx after unroll)
    #pragma unroll
    for (int c = 0; c < 4; ++c) {
        fin[0][c] = *(const f32x4*)(Xb + c * HWSZ);
        ttn[0][c] = *(const f32x4*)(Tb + c * HWSZ);
    }

    #pragma unroll
    for (int it = 0; it < ITERS; ++it) {
        const int cur = it & 1, nxt = cur ^ 1;
        if (it + 1 < ITERS) {      // prefetch next 16 pixels under this math
            #pragma unroll
            for (int c = 0; c < 4; ++c) {
                fin[nxt][c] = *(const f32x4*)(Xb + c * HWSZ + (it + 1) * 16);
                ttn[nxt][c] = *(const f32x4*)(Tb + c * HWSZ + (it + 1) * 16);
            }
        }

        unsigned int pf[8], qf[8];
        #pragma unroll
        for (int u = 0; u < 4; ++u) {          // 4 pixels per lane per iter
            float t0 = ttn[cur][0][u], t1 = ttn[cur][1][u],
                  t2 = ttn[cur][2][u], t3 = ttn[cur][3][u];

            // S = sum_c softplus(t_c) + 4 = log(prod_c (1+e^{t_c})) + 4
            float prod = (1.f + __expf(t0)) * (1.f + __expf(t1))
                       * (1.f + __expf(t2)) * (1.f + __expf(t3));
            float S    = __logf(prod) + 4.0f;
            float conf = __expf(-4.0f * rcp_hw(S));

            // p = softmax(input) (+1 shift cancels; range needs no max-sub)
            float e0 = __expf(fin[cur][0][u]), e1 = __expf(fin[cur][1][u]);
            float e2 = __expf(fin[cur][2][u]), e3 = __expf(fin[cur][3][u]);
            float inv = rcp_hw(e0 + e1 + e2 + e3);
            pf[u * 2]     = pk_bf16(e0 * inv, e1 * inv);
            pf[u * 2 + 1] = pk_bf16(e2 * inv, e3 * inv);

            // q = softmax((t+1)*conf)
            float q0 = __expf(fmaf(t0, conf, conf));
            float q1 = __expf(fmaf(t1, conf, conf));
            float q2 = __expf(fmaf(t2, conf, conf));
            float q3 = __expf(fmaf(t3, conf, conf));
            float qi = rcp_hw(q0 + q1 + q2 + q3);
            qf[u * 2]     = pk_bf16(q0 * qi, q1 * qi);
            qf[u * 2 + 1] = pk_bf16(q2 * qi, q3 * qi);
        }

        bf16x8 Pa = *(const bf16x8*)&pf[0], Pb = *(const bf16x8*)&pf[4];
        bf16x8 Qa = *(const bf16x8*)&qf[0], Qb = *(const bf16x8*)&qf[4];
        accPP = __builtin_amdgcn_mfma_f32_16x16x32_bf16(Pa, Pa, accPP, 0, 0, 0);
        accPQ = __builtin_amdgcn_mfma_f32_16x16x32_bf16(Pa, Qa, accPQ, 0, 0, 0);
        accQQ = __builtin_amdgcn_mfma_f32_16x16x32_bf16(Qa, Qa, accQQ, 0, 0, 0);
        accPP = __builtin_amdgcn_mfma_f32_16x16x32_bf16(Pb, Pb, accPP, 0, 0, 0);
        accPQ = __builtin_amdgcn_mfma_f32_16x16x32_bf16(Pb, Qb, accPQ, 0, 0, 0);
        accQQ = __builtin_amdgcn_mfma_f32_16x16x32_bf16(Qb, Qb, accQQ, 0, 0, 0);
    }

    // block-level reduction (the ONLY LDS/barrier use), then one atomic pass
    __shared__ float Gs[4][768];
    // C/D layout (m89): col = lane&15, row = (lane>>4)*4 + reg.
    // PQ: A=P -> row = P-index, B=Q -> col = Q-index.
    #pragma unroll
    for (int v = 0; v < 4; ++v) {
        int idx = (g * 4 + v) * 16 + r;
        Gs[wv][idx]       = accPP[v];
        Gs[wv][256 + idx] = accPQ[v];
        Gs[wv][512 + idx] = accQQ[v];
    }
    __syncthreads();

    float* dst = Gpart + (size_t)(blockIdx.x & (NCOPY - 1)) * 768;
    for (int e = tid; e < 768; e += 256)
        atomicAdd(&dst[e], Gs[0][e] + Gs[1][e] + Gs[2][e] + Gs[3][e]);
}

// Loss from the 3 tiles. Exact decomposition of the reference:
//  on  = 2 * sum_i (D_i - 1)^2,  D_i = (2 PQ[ii]+s)/(PP[ii]+QQ[ii]+s)
//  off = lambda * [ 2*sum_{i!=j} PQ-term + sum_{i!=j} PP-term + sum_{i!=j} QQ-term ]
//  (masked pairs are exactly the i==j entries of PP and QQ; QP = PQ^T pairs
//   give the factor 2 on the PQ terms with identical denominators)
__global__ __launch_bounds__(256) void loss_kernel(
    const float* __restrict__ Gpart, float* __restrict__ out)
{
    __shared__ float G[768];
    __shared__ float red[4];
    const int t = threadIdx.x;

    for (int e = t; e < 768; e += 256) {
        float s = 0.f;
        #pragma unroll
        for (int c = 0; c < NCOPY; ++c) s += Gpart[c * 768 + e];
        G[e] = s;
    }
    __syncthreads();

    const float* PP = G;
    const float* QQ = G + 512;
    const int i = t >> 4, j = t & 15;
    float local = 0.f;
    {   // PP tile
        float D = (2.f * G[t] + SMOOTH) / (PP[i * 17] + PP[j * 17] + SMOOTH);
        if (i != j) local += LAMBD * D * D;
    }
    {   // PQ tile (counts twice; diag is the positive pair)
        float D = (2.f * G[256 + t] + SMOOTH) / (PP[i * 17] + QQ[j * 17] + SMOOTH);
        local += (i == j) ? 2.f * (D - 1.f) * (D - 1.f) : 2.f * LAMBD * D * D;
    }
    {   // QQ tile
        float D = (2.f * G[512 + t] + SMOOTH) / (QQ[i * 17] + QQ[j * 17] + SMOOTH);
        if (i != j) local += LAMBD * D * D;
    }

    #pragma unroll
    for (int off = 32; off; off >>= 1) local += __shfl_down(local, off);
    if ((t & 63) == 0) red[t >> 6] = local;
    __syncthreads();
    if (t == 0) out[0] = red[0] + red[1] + red[2] + red[3];
}

extern "C" void kernel_launch(void* const* d_in, const int* in_sizes, int n_in,
                              void* d_out, int out_size, void* d_ws, size_t ws_size,
                              hipStream_t stream)
{
    const float* X = (const float*)d_in[0];   // input
    const float* T = (const float*)d_in[1];   // target
    float* Gpart = (float*)d_ws;              // NCOPY * 768 floats

    hipMemsetAsync(Gpart, 0, NCOPY * 768 * sizeof(float), stream);
    gram_kernel<<<1024, 256, 0, stream>>>(X, T, Gpart);
    loss_kernel<<<1, 256, 0, stream>>>(Gpart, (float*)d_out);
}